// Round 1
// baseline (1147.124 us; speedup 1.0000x reference)
//
#include <hip/hip_runtime.h>

// ---------------------------------------------------------------------------
// VGAE encoder: two GCN propagations + dense transforms.
// Aggregation commutes with the linear transform, so we aggregate raw
// features once per layer and apply the GEMMs afterwards.
// ---------------------------------------------------------------------------

// Detect whether edge_index arrived as int64 (odd int32 words all zero) or
// int32. Writes mode=1 for int64, 0 for int32.
__global__ void detect_kernel(const int* __restrict__ ei, int* __restrict__ mode) {
    if (threadIdx.x == 0 && blockIdx.x == 0) {
        int any = 0;
        for (int k = 0; k < 1024; ++k) any |= ei[2 * k + 1];
        *mode = (any == 0) ? 1 : 0;
    }
}

__global__ void count_kernel(const int* __restrict__ ei, int E, int n,
                             const int* __restrict__ mode,
                             int* __restrict__ counts) {
    int e = blockIdx.x * blockDim.x + threadIdx.x;
    if (e >= E) return;
    int m = *mode;
    int d = m ? ei[2 * (E + e)] : ei[E + e];
    if ((unsigned)d >= (unsigned)n) return;  // safety
    atomicAdd(&counts[d], 1);
}

__global__ void dinv_kernel(const int* __restrict__ counts,
                            float* __restrict__ dinv, int n) {
    int i = blockIdx.x * blockDim.x + threadIdx.x;
    if (i < n) dinv[i] = rsqrtf((float)(counts[i] + 1));  // +1 self-loop
}

// Single-block exclusive scan of counts -> row_ptr (n up to ~100k: 98 chunks).
__global__ void scan_kernel(const int* __restrict__ counts,
                            int* __restrict__ row_ptr, int n) {
    __shared__ int sdata[1024];
    __shared__ int s_base;
    int tid = threadIdx.x;
    if (tid == 0) s_base = 0;
    __syncthreads();
    for (int base = 0; base < n; base += 1024) {
        int i = base + tid;
        int v = (i < n) ? counts[i] : 0;
        sdata[tid] = v;
        __syncthreads();
        for (int off = 1; off < 1024; off <<= 1) {
            int t = (tid >= off) ? sdata[tid - off] : 0;
            __syncthreads();
            sdata[tid] += t;
            __syncthreads();
        }
        int incl = sdata[tid];
        int total = sdata[1023];
        int b = s_base;
        if (i < n) row_ptr[i] = b + incl - v;   // exclusive
        __syncthreads();
        if (tid == 0) s_base = b + total;
        __syncthreads();
    }
    if (tid == 0) row_ptr[n] = s_base;
}

__global__ void fill_kernel(const int* __restrict__ ei, int E, int n,
                            const int* __restrict__ mode,
                            const int* __restrict__ row_ptr,
                            int* __restrict__ cursor,
                            int* __restrict__ csr_src) {
    int e = blockIdx.x * blockDim.x + threadIdx.x;
    if (e >= E) return;
    int m = *mode;
    int s = m ? ei[2 * e] : ei[e];
    int d = m ? ei[2 * (E + e)] : ei[E + e];
    if ((unsigned)d >= (unsigned)n || (unsigned)s >= (unsigned)n) return;
    int pos = atomicAdd(&cursor[d], 1);
    csr_src[row_ptr[d] + pos] = s;
}

// One wave (64 lanes) per node; lane holds a float2 (128 cols).
// out[i] = dinv[i]^2 * x[i] + sum_{e in CSR row i} dinv[src]*dinv[i] * x[src]
__global__ void agg_kernel(const float* __restrict__ x,
                           const float* __restrict__ dinv,
                           const int* __restrict__ row_ptr,
                           const int* __restrict__ csr_src,
                           float* __restrict__ out, int n) {
    int wave = (int)((blockIdx.x * blockDim.x + threadIdx.x) >> 6);
    int lane = threadIdx.x & 63;
    if (wave >= n) return;
    int i = wave;
    float di = dinv[i];
    const float2* x2 = (const float2*)x;
    float2 v = x2[(size_t)i * 64 + lane];
    float w0 = di * di;
    float2 acc;
    acc.x = v.x * w0;
    acc.y = v.y * w0;
    int beg = row_ptr[i], end = row_ptr[i + 1];
    for (int e = beg; e < end; ++e) {
        int s = csr_src[e];
        float w = dinv[s] * di;
        float2 u = x2[(size_t)s * 64 + lane];
        acc.x += w * u.x;
        acc.y += w * u.y;
    }
    ((float2*)out)[(size_t)i * 64 + lane] = acc;
}

// out[r][c] = relu?( sum_k A[r][k]*W[k][c] + bias[c] )   A: [n x 128] row-major
// NCOL = 64 or 128; thread computes 8 contiguous columns of one row.
template <int NCOL, int RELU>
__global__ void gemm_kernel(const float* __restrict__ A,
                            const float* __restrict__ W,
                            const float* __restrict__ bias,
                            float* __restrict__ out, int n) {
    constexpr int CG = NCOL / 8;
    int gid = blockIdx.x * blockDim.x + threadIdx.x;
    int r = gid / CG;
    int g = gid - r * CG;
    if (r >= n) return;
    int c = g * 8;
    float acc[8];
#pragma unroll
    for (int j = 0; j < 8; ++j) acc[j] = 0.f;
    const float4* A4 = (const float4*)(A + (size_t)r * 128);
#pragma unroll 4
    for (int k = 0; k < 128; k += 4) {
        float4 a = A4[k >> 2];
#pragma unroll
        for (int kk = 0; kk < 4; ++kk) {
            float av = (kk == 0) ? a.x : (kk == 1) ? a.y : (kk == 2) ? a.z : a.w;
            float4 wlo = *(const float4*)(W + (size_t)(k + kk) * NCOL + c);
            float4 whi = *(const float4*)(W + (size_t)(k + kk) * NCOL + c + 4);
            acc[0] += av * wlo.x; acc[1] += av * wlo.y;
            acc[2] += av * wlo.z; acc[3] += av * wlo.w;
            acc[4] += av * whi.x; acc[5] += av * whi.y;
            acc[6] += av * whi.z; acc[7] += av * whi.w;
        }
    }
#pragma unroll
    for (int j = 0; j < 8; ++j) {
        float v = acc[j] + bias[c + j];
        if (RELU) v = fmaxf(v, 0.f);
        out[(size_t)r * NCOL + c + j] = v;
    }
}

extern "C" void kernel_launch(void* const* d_in, const int* in_sizes, int n_in,
                              void* d_out, int out_size, void* d_ws, size_t ws_size,
                              hipStream_t stream) {
    const float* x   = (const float*)d_in[0];
    const int*   ei  = (const int*)d_in[1];
    const float* W1  = (const float*)d_in[2];
    const float* b1  = (const float*)d_in[3];
    const float* Wmu = (const float*)d_in[4];
    const float* bmu = (const float*)d_in[5];
    const float* Wlv = (const float*)d_in[6];
    const float* blv = (const float*)d_in[7];
    float* out = (float*)d_out;

    const int n = in_sizes[0] / 128;   // 100000
    const int E = in_sizes[1] / 2;     // 1600000

    char* ws = (char*)d_ws;
    size_t off = 0;
    auto alloc = [&](size_t bytes) -> void* {
        void* p = ws + off;
        off += (bytes + 255) & ~(size_t)255;
        return p;
    };
    int*   mode    = (int*)alloc(256);
    int*   counts  = (int*)alloc((size_t)n * 4);
    int*   cursor  = (int*)alloc((size_t)n * 4);
    int*   row_ptr = (int*)alloc((size_t)(n + 1) * 4);
    float* dinv    = (float*)alloc((size_t)n * 4);
    int*   csr_src = (int*)alloc((size_t)E * 4);
    float* bufA    = (float*)alloc((size_t)n * 128 * 4);
    float* bufB    = (float*)alloc((size_t)n * 128 * 4);

    hipMemsetAsync(counts, 0, (size_t)n * 4, stream);
    hipMemsetAsync(cursor, 0, (size_t)n * 4, stream);

    detect_kernel<<<1, 64, 0, stream>>>(ei, mode);

    int eb = (E + 255) / 256;
    count_kernel<<<eb, 256, 0, stream>>>(ei, E, n, mode, counts);
    dinv_kernel<<<(n + 255) / 256, 256, 0, stream>>>(counts, dinv, n);
    scan_kernel<<<1, 1024, 0, stream>>>(counts, row_ptr, n);
    fill_kernel<<<eb, 256, 0, stream>>>(ei, E, n, mode, row_ptr, cursor, csr_src);

    int aggBlocks = (n + 3) / 4;  // 4 waves/block, 1 wave/node
    agg_kernel<<<aggBlocks, 256, 0, stream>>>(x, dinv, row_ptr, csr_src, bufA, n);

    // h = relu(agg(x) @ W1 + b1)
    gemm_kernel<128, 1><<<((size_t)n * 16 + 255) / 256, 256, 0, stream>>>(bufA, W1, b1, bufB, n);

    // ha = agg(h)  (reuse bufA)
    agg_kernel<<<aggBlocks, 256, 0, stream>>>(bufB, dinv, row_ptr, csr_src, bufA, n);

    // mu / logvar straight into d_out
    gemm_kernel<64, 0><<<((size_t)n * 8 + 255) / 256, 256, 0, stream>>>(bufA, Wmu, bmu, out, n);
    gemm_kernel<64, 0><<<((size_t)n * 8 + 255) / 256, 256, 0, stream>>>(bufA, Wlv, blv, out + (size_t)n * 64, n);
}

// Round 2
// 881.301 us; speedup vs baseline: 1.3016x; 1.3016x over previous
//
#include <hip/hip_runtime.h>

// ---------------------------------------------------------------------------
// VGAE encoder: two GCN propagations + dense transforms.
// Aggregation commutes with the linear transform, so we aggregate raw
// features once per layer and apply the GEMMs afterwards.
// ---------------------------------------------------------------------------

// Detect whether edge_index arrived as int64 (odd int32 words all zero) or
// int32. Writes mode=1 for int64, 0 for int32.
__global__ void detect_kernel(const int* __restrict__ ei, int* __restrict__ mode) {
    if (threadIdx.x == 0 && blockIdx.x == 0) {
        int any = 0;
        for (int k = 0; k < 1024; ++k) any |= ei[2 * k + 1];
        *mode = (any == 0) ? 1 : 0;
    }
}

__global__ void count_kernel(const int* __restrict__ ei, int E, int n,
                             const int* __restrict__ mode,
                             int* __restrict__ counts) {
    int e = blockIdx.x * blockDim.x + threadIdx.x;
    if (e >= E) return;
    int m = *mode;
    int d = m ? ei[2 * (E + e)] : ei[E + e];
    if ((unsigned)d >= (unsigned)n) return;  // safety
    atomicAdd(&counts[d], 1);
}

__global__ void dinv_kernel(const int* __restrict__ counts,
                            float* __restrict__ dinv, int n) {
    int i = blockIdx.x * blockDim.x + threadIdx.x;
    if (i < n) dinv[i] = rsqrtf((float)(counts[i] + 1));  // +1 self-loop
}

// Single-block exclusive scan of counts -> row_ptr (n up to ~100k: 98 chunks).
__global__ void scan_kernel(const int* __restrict__ counts,
                            int* __restrict__ row_ptr, int n) {
    __shared__ int sdata[1024];
    __shared__ int s_base;
    int tid = threadIdx.x;
    if (tid == 0) s_base = 0;
    __syncthreads();
    for (int base = 0; base < n; base += 1024) {
        int i = base + tid;
        int v = (i < n) ? counts[i] : 0;
        sdata[tid] = v;
        __syncthreads();
        for (int off = 1; off < 1024; off <<= 1) {
            int t = (tid >= off) ? sdata[tid - off] : 0;
            __syncthreads();
            sdata[tid] += t;
            __syncthreads();
        }
        int incl = sdata[tid];
        int total = sdata[1023];
        int b = s_base;
        if (i < n) row_ptr[i] = b + incl - v;   // exclusive
        __syncthreads();
        if (tid == 0) s_base = b + total;
        __syncthreads();
    }
    if (tid == 0) row_ptr[n] = s_base;
}

__global__ void fill_kernel(const int* __restrict__ ei, int E, int n,
                            const int* __restrict__ mode,
                            const int* __restrict__ row_ptr,
                            int* __restrict__ cursor,
                            int* __restrict__ csr_src) {
    int e = blockIdx.x * blockDim.x + threadIdx.x;
    if (e >= E) return;
    int m = *mode;
    int s = m ? ei[2 * e] : ei[e];
    int d = m ? ei[2 * (E + e)] : ei[E + e];
    if ((unsigned)d >= (unsigned)n || (unsigned)s >= (unsigned)n) return;
    int pos = atomicAdd(&cursor[d], 1);
    csr_src[row_ptr[d] + pos] = s;
}

// One wave (64 lanes) per node; lane holds a float2 (128 cols).
// out[i] = dinv[i]^2 * x[i] + sum_{e in CSR row i} dinv[src]*dinv[i] * x[src]
__global__ void agg_kernel(const float* __restrict__ x,
                           const float* __restrict__ dinv,
                           const int* __restrict__ row_ptr,
                           const int* __restrict__ csr_src,
                           float* __restrict__ out, int n) {
    int wave = (int)((blockIdx.x * blockDim.x + threadIdx.x) >> 6);
    int lane = threadIdx.x & 63;
    if (wave >= n) return;
    int i = wave;
    float di = dinv[i];
    const float2* x2 = (const float2*)x;
    float2 v = x2[(size_t)i * 64 + lane];
    float w0 = di * di;
    float2 acc;
    acc.x = v.x * w0;
    acc.y = v.y * w0;
    int beg = row_ptr[i], end = row_ptr[i + 1];
    for (int e = beg; e < end; ++e) {
        int s = csr_src[e];
        float w = dinv[s] * di;
        float2 u = x2[(size_t)s * 64 + lane];
        acc.x += w * u.x;
        acc.y += w * u.y;
    }
    ((float2*)out)[(size_t)i * 64 + lane] = acc;
}

// ---------------------------------------------------------------------------
// Register-tiled GEMM: A [n x 128] row-major  @  W [128 x NCOL] row-major.
// Thread layout: cg = tid%16 -> 8 contiguous cols, rg = tid/16 -> 8 contiguous
// rows. Block covers 128 rows x 128 cols. 8x8 accumulator per thread.
// Lanes with equal rg load identical A addresses (merged by HW); each W
// float4 feeds 32 FMAs.
// SPLIT=0: one NCOL=128 output (Wa/ba/outa), optional relu.
// SPLIT=1: cols 0..63 from Wa->outa (mu), 64..127 from Wb->outb (logvar),
//          each output [n x 64].
// ---------------------------------------------------------------------------
template <int SPLIT, int RELU>
__global__ __launch_bounds__(256) void gemm128_kernel(
    const float* __restrict__ A,
    const float* __restrict__ Wa, const float* __restrict__ ba,
    const float* __restrict__ Wb, const float* __restrict__ bb,
    float* __restrict__ outa, float* __restrict__ outb, int n) {
    int cg = threadIdx.x & 15;
    int rg = threadIdx.x >> 4;
    long r0 = (long)blockIdx.x * 128 + (long)rg * 8;

    const float* Wp;
    const float* bp;
    float* op;
    int ldo, c0;
    if (SPLIT) {
        if (cg < 8) { Wp = Wa; bp = ba; op = outa; }
        else        { Wp = Wb; bp = bb; op = outb; }
        ldo = 64;
        c0 = (cg & 7) * 8;
    } else {
        Wp = Wa; bp = ba; op = outa;
        ldo = 128;
        c0 = cg * 8;
    }

    // Clamp row indices for loads (stores are guarded); avoids branches in
    // the hot loop.
    long rr[8];
#pragma unroll
    for (int i = 0; i < 8; ++i) {
        long r = r0 + i;
        rr[i] = (r < n) ? r : (long)(n - 1);
    }

    float acc[8][8];
#pragma unroll
    for (int i = 0; i < 8; ++i)
#pragma unroll
        for (int j = 0; j < 8; ++j) acc[i][j] = 0.f;

    const float4* A4 = (const float4*)A;

    for (int k = 0; k < 128; k += 4) {
        float4 a[8];
#pragma unroll
        for (int i = 0; i < 8; ++i) a[i] = A4[rr[i] * 32 + (k >> 2)];
#pragma unroll
        for (int j = 0; j < 4; ++j) {
            const float* wrow = Wp + (size_t)(k + j) * ldo + c0;
            float4 w0 = *(const float4*)(wrow);
            float4 w1 = *(const float4*)(wrow + 4);
#pragma unroll
            for (int i = 0; i < 8; ++i) {
                float av = (j == 0) ? a[i].x : (j == 1) ? a[i].y
                         : (j == 2) ? a[i].z : a[i].w;
                acc[i][0] += av * w0.x; acc[i][1] += av * w0.y;
                acc[i][2] += av * w0.z; acc[i][3] += av * w0.w;
                acc[i][4] += av * w1.x; acc[i][5] += av * w1.y;
                acc[i][6] += av * w1.z; acc[i][7] += av * w1.w;
            }
        }
    }

    float4 blo = *(const float4*)(bp + c0);
    float4 bhi = *(const float4*)(bp + c0 + 4);
#pragma unroll
    for (int i = 0; i < 8; ++i) {
        long r = r0 + i;
        if (r >= n) break;
        float4 v0, v1;
        v0.x = acc[i][0] + blo.x; v0.y = acc[i][1] + blo.y;
        v0.z = acc[i][2] + blo.z; v0.w = acc[i][3] + blo.w;
        v1.x = acc[i][4] + bhi.x; v1.y = acc[i][5] + bhi.y;
        v1.z = acc[i][6] + bhi.z; v1.w = acc[i][7] + bhi.w;
        if (RELU) {
            v0.x = fmaxf(v0.x, 0.f); v0.y = fmaxf(v0.y, 0.f);
            v0.z = fmaxf(v0.z, 0.f); v0.w = fmaxf(v0.w, 0.f);
            v1.x = fmaxf(v1.x, 0.f); v1.y = fmaxf(v1.y, 0.f);
            v1.z = fmaxf(v1.z, 0.f); v1.w = fmaxf(v1.w, 0.f);
        }
        float* o = op + (size_t)r * ldo + c0;
        *(float4*)(o) = v0;
        *(float4*)(o + 4) = v1;
    }
}

extern "C" void kernel_launch(void* const* d_in, const int* in_sizes, int n_in,
                              void* d_out, int out_size, void* d_ws, size_t ws_size,
                              hipStream_t stream) {
    const float* x   = (const float*)d_in[0];
    const int*   ei  = (const int*)d_in[1];
    const float* W1  = (const float*)d_in[2];
    const float* b1  = (const float*)d_in[3];
    const float* Wmu = (const float*)d_in[4];
    const float* bmu = (const float*)d_in[5];
    const float* Wlv = (const float*)d_in[6];
    const float* blv = (const float*)d_in[7];
    float* out = (float*)d_out;

    const int n = in_sizes[0] / 128;   // 100000
    const int E = in_sizes[1] / 2;     // 1600000

    char* ws = (char*)d_ws;
    size_t off = 0;
    auto alloc = [&](size_t bytes) -> void* {
        void* p = ws + off;
        off += (bytes + 255) & ~(size_t)255;
        return p;
    };
    int*   mode    = (int*)alloc(256);
    int*   counts  = (int*)alloc((size_t)n * 4);
    int*   cursor  = (int*)alloc((size_t)n * 4);
    int*   row_ptr = (int*)alloc((size_t)(n + 1) * 4);
    float* dinv    = (float*)alloc((size_t)n * 4);
    int*   csr_src = (int*)alloc((size_t)E * 4);
    float* bufA    = (float*)alloc((size_t)n * 128 * 4);
    float* bufB    = (float*)alloc((size_t)n * 128 * 4);

    hipMemsetAsync(counts, 0, (size_t)n * 4, stream);
    hipMemsetAsync(cursor, 0, (size_t)n * 4, stream);

    detect_kernel<<<1, 64, 0, stream>>>(ei, mode);

    int eb = (E + 255) / 256;
    count_kernel<<<eb, 256, 0, stream>>>(ei, E, n, mode, counts);
    dinv_kernel<<<(n + 255) / 256, 256, 0, stream>>>(counts, dinv, n);
    scan_kernel<<<1, 1024, 0, stream>>>(counts, row_ptr, n);
    fill_kernel<<<eb, 256, 0, stream>>>(ei, E, n, mode, row_ptr, cursor, csr_src);

    int aggBlocks = (n + 3) / 4;  // 4 waves/block, 1 wave/node
    agg_kernel<<<aggBlocks, 256, 0, stream>>>(x, dinv, row_ptr, csr_src, bufA, n);

    int gb = (n + 127) / 128;
    // h = relu(agg(x) @ W1 + b1)
    gemm128_kernel<0, 1><<<gb, 256, 0, stream>>>(bufA, W1, b1, nullptr, nullptr,
                                                 bufB, nullptr, n);

    // ha = agg(h)  (reuse bufA)
    agg_kernel<<<aggBlocks, 256, 0, stream>>>(bufB, dinv, row_ptr, csr_src, bufA, n);

    // mu / logvar fused: read ha once, write both output slabs
    gemm128_kernel<1, 0><<<gb, 256, 0, stream>>>(bufA, Wmu, bmu, Wlv, blv,
                                                 out, out + (size_t)n * 64, n);
}

// Round 3
// 573.471 us; speedup vs baseline: 2.0003x; 1.5368x over previous
//
#include <hip/hip_runtime.h>
#include <hip/hip_fp16.h>

// ---------------------------------------------------------------------------
// VGAE encoder: two GCN propagations + dense transforms.
// agg commutes with the right-multiply, so aggregate once per layer and do
// the GEMMs afterwards. Gathers run on fp16 copies of the features (halves
// random-gather bytes); accumulation is fp32.
// ---------------------------------------------------------------------------

// Detect whether edge_index arrived as int64 (odd int32 words all zero) or
// int32. Writes mode=1 for int64, 0 for int32.
__global__ void detect_kernel(const int* __restrict__ ei, int* __restrict__ mode) {
    if (threadIdx.x == 0 && blockIdx.x == 0) {
        int any = 0;
        for (int k = 0; k < 1024; ++k) any |= ei[2 * k + 1];
        *mode = (any == 0) ? 1 : 0;
    }
}

__global__ void count_kernel(const int* __restrict__ ei, int E, int n,
                             const int* __restrict__ mode,
                             int* __restrict__ counts) {
    int e = blockIdx.x * blockDim.x + threadIdx.x;
    if (e >= E) return;
    int m = *mode;
    int d = m ? ei[2 * (E + e)] : ei[E + e];
    if ((unsigned)d >= (unsigned)n) return;  // safety
    atomicAdd(&counts[d], 1);
}

__global__ void dinv_kernel(const int* __restrict__ counts,
                            float* __restrict__ dinv, int n) {
    int i = blockIdx.x * blockDim.x + threadIdx.x;
    if (i < n) dinv[i] = rsqrtf((float)(counts[i] + 1));  // +1 self-loop
}

// Single-block exclusive scan: wave shuffle scan + cross-wave scan.
__global__ void scan_kernel(const int* __restrict__ counts,
                            int* __restrict__ row_ptr, int n) {
    __shared__ int woff[17];
    __shared__ int s_base;
    int tid = threadIdx.x, lane = tid & 63, wid = tid >> 6;
    if (tid == 0) s_base = 0;
    __syncthreads();
    for (int base = 0; base < n; base += 1024) {
        int i = base + tid;
        int v = (i < n) ? counts[i] : 0;
        int incl = v;
#pragma unroll
        for (int off = 1; off < 64; off <<= 1) {
            int t = __shfl_up(incl, off, 64);
            if (lane >= off) incl += t;
        }
        if (lane == 63) woff[wid + 1] = incl;  // wave total
        __syncthreads();
        if (tid == 0) {
            int acc = 0;
            woff[0] = 0;
            for (int w = 1; w <= 16; ++w) { acc += woff[w]; woff[w] = acc; }
        }
        __syncthreads();
        int b = s_base;
        if (i < n) row_ptr[i] = b + woff[wid] + incl - v;  // exclusive
        int total = woff[16];
        __syncthreads();
        if (tid == 0) s_base = b + total;
        __syncthreads();
    }
    if (threadIdx.x == 0) row_ptr[n] = s_base;
}

__global__ void fill_kernel(const int* __restrict__ ei, int E, int n,
                            const int* __restrict__ mode,
                            const int* __restrict__ row_ptr,
                            const float* __restrict__ dinv,
                            int* __restrict__ cursor,
                            int* __restrict__ csr_src,
                            float* __restrict__ csr_w) {
    int e = blockIdx.x * blockDim.x + threadIdx.x;
    if (e >= E) return;
    int m = *mode;
    int s = m ? ei[2 * e] : ei[e];
    int d = m ? ei[2 * (E + e)] : ei[E + e];
    if ((unsigned)d >= (unsigned)n || (unsigned)s >= (unsigned)n) return;
    int pos = atomicAdd(&cursor[d], 1);
    int idx = row_ptr[d] + pos;
    csr_src[idx] = s;
    csr_w[idx] = dinv[s];
}

// fp32 -> fp16 conversion, 8 elements/thread.
__global__ void f2h_kernel(const float* __restrict__ in,
                           __half* __restrict__ out, int count8) {
    int i = blockIdx.x * blockDim.x + threadIdx.x;
    if (i >= count8) return;
    float4 a = ((const float4*)in)[2 * i];
    float4 b = ((const float4*)in)[2 * i + 1];
    __half2 h[4];
    h[0] = __floats2half2_rn(a.x, a.y);
    h[1] = __floats2half2_rn(a.z, a.w);
    h[2] = __floats2half2_rn(b.x, b.y);
    h[3] = __floats2half2_rn(b.z, b.w);
    ((float4*)out)[i] = *(float4*)h;
}

// One wave per node; lane holds a half2 (128 cols). 4-wide edge unroll for
// memory-level parallelism. out = di^2 * x[i] + di * sum_e w_e * x[src_e]
__global__ __launch_bounds__(256) void agg_kernel(
    const __half* __restrict__ xh, const float* __restrict__ dinv,
    const int* __restrict__ row_ptr, const int* __restrict__ csr_src,
    const float* __restrict__ csr_w, float* __restrict__ out, int n) {
    int wave = (int)((blockIdx.x * blockDim.x + threadIdx.x) >> 6);
    int lane = threadIdx.x & 63;
    if (wave >= n) return;
    const __half2* x2 = (const __half2*)xh;
    float di = dinv[wave];
    float2 xf = __half22float2(x2[((size_t)wave << 6) + lane]);
    float accx = 0.f, accy = 0.f;
    int e = row_ptr[wave], end = row_ptr[wave + 1];
    for (; e + 4 <= end; e += 4) {
        int s0 = csr_src[e + 0], s1 = csr_src[e + 1];
        int s2 = csr_src[e + 2], s3 = csr_src[e + 3];
        float w0 = csr_w[e + 0], w1 = csr_w[e + 1];
        float w2 = csr_w[e + 2], w3 = csr_w[e + 3];
        float2 u0 = __half22float2(x2[((size_t)s0 << 6) + lane]);
        float2 u1 = __half22float2(x2[((size_t)s1 << 6) + lane]);
        float2 u2 = __half22float2(x2[((size_t)s2 << 6) + lane]);
        float2 u3 = __half22float2(x2[((size_t)s3 << 6) + lane]);
        accx += w0 * u0.x; accy += w0 * u0.y;
        accx += w1 * u1.x; accy += w1 * u1.y;
        accx += w2 * u2.x; accy += w2 * u2.y;
        accx += w3 * u3.x; accy += w3 * u3.y;
    }
    for (; e < end; ++e) {
        int s = csr_src[e];
        float w = csr_w[e];
        float2 u = __half22float2(x2[((size_t)s << 6) + lane]);
        accx += w * u.x; accy += w * u.y;
    }
    float2 o;
    o.x = di * (di * xf.x + accx);
    o.y = di * (di * xf.y + accy);
    ((float2*)out)[((size_t)wave << 6) + lane] = o;
}

// ---------------------------------------------------------------------------
// Register-tiled GEMM: A [n x 128] f32 row-major  @  W [128 x NCOL] row-major.
// cg = tid%16 -> 8 contiguous cols, rg = tid/16 -> 8 rows. 8x8 acc/thread.
// SPLIT=0: one 128-col output; HOUT picks fp16 vs fp32 output.
// SPLIT=1: cols 0..63 from Wa->outa (mu), 64..127 from Wb->outb (logvar).
// ---------------------------------------------------------------------------
template <int SPLIT, int RELU, int HOUT>
__global__ __launch_bounds__(256) void gemm128_kernel(
    const float* __restrict__ A,
    const float* __restrict__ Wa, const float* __restrict__ ba,
    const float* __restrict__ Wb, const float* __restrict__ bb,
    void* __restrict__ outa, void* __restrict__ outb, int n) {
    int cg = threadIdx.x & 15;
    int rg = threadIdx.x >> 4;
    long r0 = (long)blockIdx.x * 128 + (long)rg * 8;

    const float* Wp;
    const float* bp;
    void* op;
    int ldo, c0;
    if (SPLIT) {
        if (cg < 8) { Wp = Wa; bp = ba; op = outa; }
        else        { Wp = Wb; bp = bb; op = outb; }
        ldo = 64;
        c0 = (cg & 7) * 8;
    } else {
        Wp = Wa; bp = ba; op = outa;
        ldo = 128;
        c0 = cg * 8;
    }

    long rr[8];
#pragma unroll
    for (int i = 0; i < 8; ++i) {
        long r = r0 + i;
        rr[i] = (r < n) ? r : (long)(n - 1);
    }

    float acc[8][8];
#pragma unroll
    for (int i = 0; i < 8; ++i)
#pragma unroll
        for (int j = 0; j < 8; ++j) acc[i][j] = 0.f;

    const float4* A4 = (const float4*)A;

    for (int k = 0; k < 128; k += 4) {
        float4 a[8];
#pragma unroll
        for (int i = 0; i < 8; ++i) a[i] = A4[rr[i] * 32 + (k >> 2)];
#pragma unroll
        for (int j = 0; j < 4; ++j) {
            const float* wrow = Wp + (size_t)(k + j) * ldo + c0;
            float4 w0 = *(const float4*)(wrow);
            float4 w1 = *(const float4*)(wrow + 4);
#pragma unroll
            for (int i = 0; i < 8; ++i) {
                float av = (j == 0) ? a[i].x : (j == 1) ? a[i].y
                         : (j == 2) ? a[i].z : a[i].w;
                acc[i][0] += av * w0.x; acc[i][1] += av * w0.y;
                acc[i][2] += av * w0.z; acc[i][3] += av * w0.w;
                acc[i][4] += av * w1.x; acc[i][5] += av * w1.y;
                acc[i][6] += av * w1.z; acc[i][7] += av * w1.w;
            }
        }
    }

    float4 blo = *(const float4*)(bp + c0);
    float4 bhi = *(const float4*)(bp + c0 + 4);
#pragma unroll
    for (int i = 0; i < 8; ++i) {
        long r = r0 + i;
        if (r >= n) break;
        float v[8];
        v[0] = acc[i][0] + blo.x; v[1] = acc[i][1] + blo.y;
        v[2] = acc[i][2] + blo.z; v[3] = acc[i][3] + blo.w;
        v[4] = acc[i][4] + bhi.x; v[5] = acc[i][5] + bhi.y;
        v[6] = acc[i][6] + bhi.z; v[7] = acc[i][7] + bhi.w;
        if (RELU) {
#pragma unroll
            for (int j = 0; j < 8; ++j) v[j] = fmaxf(v[j], 0.f);
        }
        if (HOUT) {
            __half2 h[4];
#pragma unroll
            for (int j = 0; j < 4; ++j)
                h[j] = __floats2half2_rn(v[2 * j], v[2 * j + 1]);
            *(float4*)((__half*)op + (size_t)r * ldo + c0) = *(float4*)h;
        } else {
            float4 v0 = make_float4(v[0], v[1], v[2], v[3]);
            float4 v1 = make_float4(v[4], v[5], v[6], v[7]);
            float* o = (float*)op + (size_t)r * ldo + c0;
            *(float4*)(o) = v0;
            *(float4*)(o + 4) = v1;
        }
    }
}

extern "C" void kernel_launch(void* const* d_in, const int* in_sizes, int n_in,
                              void* d_out, int out_size, void* d_ws, size_t ws_size,
                              hipStream_t stream) {
    const float* x   = (const float*)d_in[0];
    const int*   ei  = (const int*)d_in[1];
    const float* W1  = (const float*)d_in[2];
    const float* b1  = (const float*)d_in[3];
    const float* Wmu = (const float*)d_in[4];
    const float* bmu = (const float*)d_in[5];
    const float* Wlv = (const float*)d_in[6];
    const float* blv = (const float*)d_in[7];
    float* out = (float*)d_out;

    const int n = in_sizes[0] / 128;   // 100000
    const int E = in_sizes[1] / 2;     // 1600000

    char* ws = (char*)d_ws;
    size_t off = 0;
    auto alloc = [&](size_t bytes) -> void* {
        void* p = ws + off;
        off += (bytes + 255) & ~(size_t)255;
        return p;
    };
    int*   mode    = (int*)alloc(256);
    int*   counts  = (int*)alloc((size_t)n * 4);
    int*   cursor  = (int*)alloc((size_t)n * 4);
    int*   row_ptr = (int*)alloc((size_t)(n + 1) * 4);
    float* dinv    = (float*)alloc((size_t)n * 4);
    int*   csr_src = (int*)alloc((size_t)E * 4);
    float* csr_w   = (float*)alloc((size_t)E * 4);
    __half* xh     = (__half*)alloc((size_t)n * 128 * 2);  // x fp16, then h fp16
    float* bufA    = (float*)alloc((size_t)n * 128 * 4);   // agg outputs (f32)

    hipMemsetAsync(counts, 0, (size_t)n * 4, stream);
    hipMemsetAsync(cursor, 0, (size_t)n * 4, stream);

    detect_kernel<<<1, 64, 0, stream>>>(ei, mode);

    int eb = (E + 255) / 256;
    count_kernel<<<eb, 256, 0, stream>>>(ei, E, n, mode, counts);
    dinv_kernel<<<(n + 255) / 256, 256, 0, stream>>>(counts, dinv, n);
    scan_kernel<<<1, 1024, 0, stream>>>(counts, row_ptr, n);
    fill_kernel<<<eb, 256, 0, stream>>>(ei, E, n, mode, row_ptr, dinv,
                                        cursor, csr_src, csr_w);

    int count8 = n * 16;  // n*128/8
    f2h_kernel<<<(count8 + 255) / 256, 256, 0, stream>>>(x, xh, count8);

    int aggBlocks = (n + 3) / 4;  // 4 waves/block, 1 wave/node
    // bufA = agg(x)
    agg_kernel<<<aggBlocks, 256, 0, stream>>>(xh, dinv, row_ptr, csr_src,
                                              csr_w, bufA, n);
    // h(fp16, into xh) = relu(bufA @ W1 + b1)
    int gb = (n + 127) / 128;
    gemm128_kernel<0, 1, 1><<<gb, 256, 0, stream>>>(bufA, W1, b1, nullptr,
                                                    nullptr, xh, nullptr, n);
    // bufA = agg(h)
    agg_kernel<<<aggBlocks, 256, 0, stream>>>(xh, dinv, row_ptr, csr_src,
                                              csr_w, bufA, n);
    // mu / logvar fused: read ha once, write both output slabs
    gemm128_kernel<1, 0, 0><<<gb, 256, 0, stream>>>(bufA, Wmu, bmu, Wlv, blv,
                                                    out, out + (size_t)n * 64, n);
}

// Round 4
// 511.824 us; speedup vs baseline: 2.2412x; 1.1204x over previous
//
#include <hip/hip_runtime.h>
#include <hip/hip_fp16.h>

// ---------------------------------------------------------------------------
// VGAE encoder: two GCN propagations + dense transforms.
// agg commutes with the right-multiply, so aggregate once per layer and do
// the GEMMs afterwards. Gathers and intermediate features are fp16 (halves
// random-gather bytes); all accumulation is fp32.
// ---------------------------------------------------------------------------

// Detect whether edge_index arrived as int64 (odd int32 words all zero) or
// int32. Wave-parallel. Writes mode=1 for int64, 0 for int32.
__global__ void detect_kernel(const int* __restrict__ ei, int* __restrict__ mode) {
    int lane = threadIdx.x & 63;
    int any = 0;
    for (int k = lane; k < 1024; k += 64) any |= ei[2 * k + 1];
    unsigned long long b = __ballot(any != 0);
    if (threadIdx.x == 0) *mode = (b == 0ull) ? 1 : 0;
}

__global__ void count_kernel(const int* __restrict__ ei, int E, int n,
                             const int* __restrict__ mode,
                             int* __restrict__ counts) {
    int e = blockIdx.x * blockDim.x + threadIdx.x;
    if (e >= E) return;
    int m = *mode;
    int d = m ? ei[2 * (E + e)] : ei[E + e];
    if ((unsigned)d >= (unsigned)n) return;  // safety
    atomicAdd(&counts[d], 1);
}

// Pass 1: per-block (1024-wide) exclusive scan of counts into row_ptr
// (block-local base), block totals into blk. Also computes dinv.
__global__ __launch_bounds__(1024) void scan1_kernel(
    const int* __restrict__ counts, int* __restrict__ row_ptr,
    int* __restrict__ blk, float* __restrict__ dinv, int n) {
    __shared__ int woff[17];
    int tid = threadIdx.x, lane = tid & 63, wid = tid >> 6;
    int i = blockIdx.x * 1024 + tid;
    int v = (i < n) ? counts[i] : 0;
    if (i < n) dinv[i] = rsqrtf((float)(v + 1));  // +1 self-loop
    int incl = v;
#pragma unroll
    for (int off = 1; off < 64; off <<= 1) {
        int t = __shfl_up(incl, off, 64);
        if (lane >= off) incl += t;
    }
    if (lane == 63) woff[wid + 1] = incl;
    __syncthreads();
    if (tid == 0) {
        int acc = 0;
        woff[0] = 0;
#pragma unroll
        for (int w = 1; w <= 16; ++w) { acc += woff[w]; woff[w] = acc; }
        blk[blockIdx.x] = acc;
    }
    __syncthreads();
    if (i < n) row_ptr[i] = woff[wid] + incl - v;  // block-local exclusive
}

// Pass 2: exclusive scan of nb (<=128) block totals; writes grand total to
// row_ptr_n (= row_ptr + n).
__global__ void scan2_kernel(const int* __restrict__ blk,
                             int* __restrict__ blk_off,
                             int* __restrict__ row_ptr_n, int nb) {
    __shared__ int w0sum;
    int tid = threadIdx.x, lane = tid & 63, wid = tid >> 6;
    int v = (tid < nb) ? blk[tid] : 0;
    int incl = v;
#pragma unroll
    for (int off = 1; off < 64; off <<= 1) {
        int t = __shfl_up(incl, off, 64);
        if (lane >= off) incl += t;
    }
    if (wid == 0 && lane == 63) w0sum = incl;
    __syncthreads();
    int excl = incl - v + (wid ? w0sum : 0);
    if (tid < nb) blk_off[tid] = excl;
    if (tid == nb - 1) *row_ptr_n = excl + v;
}

// Pass 3: add block offsets.
__global__ __launch_bounds__(1024) void scan3_kernel(
    int* __restrict__ row_ptr, const int* __restrict__ blk_off, int n) {
    int i = blockIdx.x * 1024 + threadIdx.x;
    if (i < n) row_ptr[i] += blk_off[blockIdx.x];
}

__global__ void fill_kernel(const int* __restrict__ ei, int E, int n,
                            const int* __restrict__ mode,
                            const int* __restrict__ row_ptr,
                            int* __restrict__ cursor,
                            int* __restrict__ csr_src) {
    int e = blockIdx.x * blockDim.x + threadIdx.x;
    if (e >= E) return;
    int m = *mode;
    int s = m ? ei[2 * e] : ei[e];
    int d = m ? ei[2 * (E + e)] : ei[E + e];
    if ((unsigned)d >= (unsigned)n || (unsigned)s >= (unsigned)n) return;
    int pos = atomicAdd(&cursor[d], 1);
    csr_src[row_ptr[d] + pos] = s;
}

// fp32 -> fp16 conversion, 8 elements/thread.
__global__ void f2h_kernel(const float* __restrict__ in,
                           __half* __restrict__ out, int count8) {
    int i = blockIdx.x * blockDim.x + threadIdx.x;
    if (i >= count8) return;
    float4 a = ((const float4*)in)[2 * i];
    float4 b = ((const float4*)in)[2 * i + 1];
    __half2 h[4];
    h[0] = __floats2half2_rn(a.x, a.y);
    h[1] = __floats2half2_rn(a.z, a.w);
    h[2] = __floats2half2_rn(b.x, b.y);
    h[3] = __floats2half2_rn(b.z, b.w);
    ((float4*)out)[i] = *(float4*)h;
}

// One wave per node; lane holds a half2 (128 cols). 8-wide edge unroll.
// Src index scalarized via readfirstlane: SGPR base + lane offset loads,
// dinv[s] via scalar load. out(fp16) = di * (di*x[i] + sum_e dinv[s]*x[s])
__global__ __launch_bounds__(256) void agg_kernel(
    const __half* __restrict__ xh, const float* __restrict__ dinv,
    const int* __restrict__ row_ptr, const int* __restrict__ csr_src,
    __half* __restrict__ outh, int n) {
    int wave = (int)((blockIdx.x * blockDim.x + threadIdx.x) >> 6);
    int lane = threadIdx.x & 63;
    if (wave >= n) return;
    const __half2* x2 = (const __half2*)xh;
    float di = dinv[wave];
    float2 xf = __half22float2(x2[((size_t)wave << 6) + lane]);
    float accx = 0.f, accy = 0.f;
    int e = row_ptr[wave], end = row_ptr[wave + 1];
    for (; e + 8 <= end; e += 8) {
        int s[8];
        float w[8];
        float2 u[8];
#pragma unroll
        for (int k = 0; k < 8; ++k)
            s[k] = __builtin_amdgcn_readfirstlane(csr_src[e + k]);
#pragma unroll
        for (int k = 0; k < 8; ++k) w[k] = dinv[s[k]];
#pragma unroll
        for (int k = 0; k < 8; ++k)
            u[k] = __half22float2(x2[((size_t)s[k] << 6) + lane]);
#pragma unroll
        for (int k = 0; k < 8; ++k) {
            accx += w[k] * u[k].x;
            accy += w[k] * u[k].y;
        }
    }
    for (; e < end; ++e) {
        int s = __builtin_amdgcn_readfirstlane(csr_src[e]);
        float w = dinv[s];
        float2 u = __half22float2(x2[((size_t)s << 6) + lane]);
        accx += w * u.x;
        accy += w * u.y;
    }
    __half2 o = __floats2half2_rn(di * (di * xf.x + accx),
                                  di * (di * xf.y + accy));
    ((__half2*)outh)[((size_t)wave << 6) + lane] = o;
}

// ---------------------------------------------------------------------------
// Register-tiled GEMM: A [n x 128] fp16 row-major  @  W [128 x NCOL] f32
// row-major. cg = tid%16 -> 8 contiguous cols, rg = tid/16 -> 8 rows.
// 8x8 fp32 acc/thread. SPLIT=0: one 128-col output (HOUT: fp16 or fp32).
// SPLIT=1: cols 0..63 from Wa->outa (mu), 64..127 from Wb->outb (logvar).
// ---------------------------------------------------------------------------
template <int SPLIT, int RELU, int HOUT>
__global__ __launch_bounds__(256) void gemm128_kernel(
    const __half* __restrict__ A,
    const float* __restrict__ Wa, const float* __restrict__ ba,
    const float* __restrict__ Wb, const float* __restrict__ bb,
    void* __restrict__ outa, void* __restrict__ outb, int n) {
    int cg = threadIdx.x & 15;
    int rg = threadIdx.x >> 4;
    long r0 = (long)blockIdx.x * 128 + (long)rg * 8;

    const float* Wp;
    const float* bp;
    void* op;
    int ldo, c0;
    if (SPLIT) {
        if (cg < 8) { Wp = Wa; bp = ba; op = outa; }
        else        { Wp = Wb; bp = bb; op = outb; }
        ldo = 64;
        c0 = (cg & 7) * 8;
    } else {
        Wp = Wa; bp = ba; op = outa;
        ldo = 128;
        c0 = cg * 8;
    }

    long rr[8];
#pragma unroll
    for (int i = 0; i < 8; ++i) {
        long r = r0 + i;
        rr[i] = (r < n) ? r : (long)(n - 1);
    }

    float acc[8][8];
#pragma unroll
    for (int i = 0; i < 8; ++i)
#pragma unroll
        for (int j = 0; j < 8; ++j) acc[i][j] = 0.f;

    const float4* A8 = (const float4*)A;  // 8 halves per float4; row = 16

    for (int k = 0; k < 128; k += 8) {
        float4 araw[8];
#pragma unroll
        for (int i = 0; i < 8; ++i) araw[i] = A8[rr[i] * 16 + (k >> 3)];
#pragma unroll
        for (int jp = 0; jp < 4; ++jp) {
            float2 af[8];
#pragma unroll
            for (int i = 0; i < 8; ++i) {
                const __half2* ah = ((const __half2*)&araw[i]) + jp;
                af[i] = __half22float2(*ah);
            }
#pragma unroll
            for (int sub = 0; sub < 2; ++sub) {
                int kk = k + 2 * jp + sub;
                const float* wrow = Wp + (size_t)kk * ldo + c0;
                float4 w0 = *(const float4*)(wrow);
                float4 w1 = *(const float4*)(wrow + 4);
#pragma unroll
                for (int i = 0; i < 8; ++i) {
                    float av = sub ? af[i].y : af[i].x;
                    acc[i][0] += av * w0.x; acc[i][1] += av * w0.y;
                    acc[i][2] += av * w0.z; acc[i][3] += av * w0.w;
                    acc[i][4] += av * w1.x; acc[i][5] += av * w1.y;
                    acc[i][6] += av * w1.z; acc[i][7] += av * w1.w;
                }
            }
        }
    }

    float4 blo = *(const float4*)(bp + c0);
    float4 bhi = *(const float4*)(bp + c0 + 4);
#pragma unroll
    for (int i = 0; i < 8; ++i) {
        long r = r0 + i;
        if (r >= n) break;
        float v[8];
        v[0] = acc[i][0] + blo.x; v[1] = acc[i][1] + blo.y;
        v[2] = acc[i][2] + blo.z; v[3] = acc[i][3] + blo.w;
        v[4] = acc[i][4] + bhi.x; v[5] = acc[i][5] + bhi.y;
        v[6] = acc[i][6] + bhi.z; v[7] = acc[i][7] + bhi.w;
        if (RELU) {
#pragma unroll
            for (int j = 0; j < 8; ++j) v[j] = fmaxf(v[j], 0.f);
        }
        if (HOUT) {
            __half2 h[4];
#pragma unroll
            for (int j = 0; j < 4; ++j)
                h[j] = __floats2half2_rn(v[2 * j], v[2 * j + 1]);
            *(float4*)((__half*)op + (size_t)r * ldo + c0) = *(float4*)h;
        } else {
            float4 v0 = make_float4(v[0], v[1], v[2], v[3]);
            float4 v1 = make_float4(v[4], v[5], v[6], v[7]);
            float* o = (float*)op + (size_t)r * ldo + c0;
            *(float4*)(o) = v0;
            *(float4*)(o + 4) = v1;
        }
    }
}

extern "C" void kernel_launch(void* const* d_in, const int* in_sizes, int n_in,
                              void* d_out, int out_size, void* d_ws, size_t ws_size,
                              hipStream_t stream) {
    const float* x   = (const float*)d_in[0];
    const int*   ei  = (const int*)d_in[1];
    const float* W1  = (const float*)d_in[2];
    const float* b1  = (const float*)d_in[3];
    const float* Wmu = (const float*)d_in[4];
    const float* bmu = (const float*)d_in[5];
    const float* Wlv = (const float*)d_in[6];
    const float* blv = (const float*)d_in[7];
    float* out = (float*)d_out;

    const int n = in_sizes[0] / 128;   // 100000
    const int E = in_sizes[1] / 2;     // 1600000
    const int nb = (n + 1023) / 1024;  // scan blocks (98)

    char* ws = (char*)d_ws;
    size_t off = 0;
    auto alloc = [&](size_t bytes) -> void* {
        void* p = ws + off;
        off += (bytes + 255) & ~(size_t)255;
        return p;
    };
    int*   mode    = (int*)alloc(256);
    int*   counts  = (int*)alloc((size_t)n * 4);
    int*   cursor  = (int*)alloc((size_t)n * 4);
    int*   row_ptr = (int*)alloc((size_t)(n + 1) * 4);
    int*   blk     = (int*)alloc((size_t)nb * 4);
    int*   blk_off = (int*)alloc((size_t)nb * 4);
    float* dinv    = (float*)alloc((size_t)n * 4);
    int*   csr_src = (int*)alloc((size_t)E * 4);
    __half* xh     = (__half*)alloc((size_t)n * 128 * 2);  // x fp16, then h fp16
    __half* bufAh  = (__half*)alloc((size_t)n * 128 * 2);  // agg outputs (fp16)

    hipMemsetAsync(counts, 0, (size_t)n * 4, stream);
    hipMemsetAsync(cursor, 0, (size_t)n * 4, stream);

    detect_kernel<<<1, 64, 0, stream>>>(ei, mode);

    int eb = (E + 255) / 256;
    count_kernel<<<eb, 256, 0, stream>>>(ei, E, n, mode, counts);
    scan1_kernel<<<nb, 1024, 0, stream>>>(counts, row_ptr, blk, dinv, n);
    scan2_kernel<<<1, 128, 0, stream>>>(blk, blk_off, row_ptr + n, nb);
    scan3_kernel<<<nb, 1024, 0, stream>>>(row_ptr, blk_off, n);
    fill_kernel<<<eb, 256, 0, stream>>>(ei, E, n, mode, row_ptr, cursor, csr_src);

    int count8 = n * 16;  // n*128/8
    f2h_kernel<<<(count8 + 255) / 256, 256, 0, stream>>>(x, xh, count8);

    int aggBlocks = (n + 3) / 4;  // 4 waves/block, 1 wave/node
    // bufAh = agg(x)  (fp16)
    agg_kernel<<<aggBlocks, 256, 0, stream>>>(xh, dinv, row_ptr, csr_src,
                                              bufAh, n);
    // h(fp16, into xh) = relu(bufAh @ W1 + b1)
    int gb = (n + 127) / 128;
    gemm128_kernel<0, 1, 1><<<gb, 256, 0, stream>>>(bufAh, W1, b1, nullptr,
                                                    nullptr, xh, nullptr, n);
    // bufAh = agg(h)
    agg_kernel<<<aggBlocks, 256, 0, stream>>>(xh, dinv, row_ptr, csr_src,
                                              bufAh, n);
    // mu / logvar fused: read ha once, write both output slabs (f32)
    gemm128_kernel<1, 0, 0><<<gb, 256, 0, stream>>>(bufAh, Wmu, bmu, Wlv, blv,
                                                    out, out + (size_t)n * 64, n);
}

// Round 5
// 372.187 us; speedup vs baseline: 3.0821x; 1.3752x over previous
//
#include <hip/hip_runtime.h>
#include <hip/hip_fp16.h>

// ---------------------------------------------------------------------------
// VGAE encoder: two GCN propagations + dense transforms.
// agg commutes with the right-multiply, so aggregate once per layer and do
// the GEMMs afterwards. Gathers and intermediate features are fp16 (halves
// random-gather bytes); GEMMs run on MFMA f16 with fp32 accumulation.
// ---------------------------------------------------------------------------

using half8 = __attribute__((ext_vector_type(8))) _Float16;
using f32x4 = __attribute__((ext_vector_type(4))) float;

// Detect whether edge_index arrived as int64 (odd int32 words all zero) or
// int32. Wave-parallel. Writes mode=1 for int64, 0 for int32.
__global__ void detect_kernel(const int* __restrict__ ei, int* __restrict__ mode) {
    int lane = threadIdx.x & 63;
    int any = 0;
    for (int k = lane; k < 1024; k += 64) any |= ei[2 * k + 1];
    unsigned long long b = __ballot(any != 0);
    if (threadIdx.x == 0) *mode = (b == 0ull) ? 1 : 0;
}

__global__ void count_kernel(const int* __restrict__ ei, int E, int n,
                             const int* __restrict__ mode,
                             int* __restrict__ counts) {
    int e = blockIdx.x * blockDim.x + threadIdx.x;
    if (e >= E) return;
    int m = *mode;
    int d = m ? ei[2 * (E + e)] : ei[E + e];
    if ((unsigned)d >= (unsigned)n) return;  // safety
    atomicAdd(&counts[d], 1);
}

// Pass 1: per-block (1024-wide) exclusive scan of counts into row_ptr
// (block-local base), block totals into blk. Also computes dinv.
__global__ __launch_bounds__(1024) void scan1_kernel(
    const int* __restrict__ counts, int* __restrict__ row_ptr,
    int* __restrict__ blk, float* __restrict__ dinv, int n) {
    __shared__ int woff[17];
    int tid = threadIdx.x, lane = tid & 63, wid = tid >> 6;
    int i = blockIdx.x * 1024 + tid;
    int v = (i < n) ? counts[i] : 0;
    if (i < n) dinv[i] = rsqrtf((float)(v + 1));  // +1 self-loop
    int incl = v;
#pragma unroll
    for (int off = 1; off < 64; off <<= 1) {
        int t = __shfl_up(incl, off, 64);
        if (lane >= off) incl += t;
    }
    if (lane == 63) woff[wid + 1] = incl;
    __syncthreads();
    if (tid == 0) {
        int acc = 0;
        woff[0] = 0;
#pragma unroll
        for (int w = 1; w <= 16; ++w) { acc += woff[w]; woff[w] = acc; }
        blk[blockIdx.x] = acc;
    }
    __syncthreads();
    if (i < n) row_ptr[i] = woff[wid] + incl - v;  // block-local exclusive
}

// Pass 2: exclusive scan of nb (<=128) block totals; writes grand total to
// row_ptr_n (= row_ptr + n).
__global__ void scan2_kernel(const int* __restrict__ blk,
                             int* __restrict__ blk_off,
                             int* __restrict__ row_ptr_n, int nb) {
    __shared__ int w0sum;
    int tid = threadIdx.x, lane = tid & 63, wid = tid >> 6;
    int v = (tid < nb) ? blk[tid] : 0;
    int incl = v;
#pragma unroll
    for (int off = 1; off < 64; off <<= 1) {
        int t = __shfl_up(incl, off, 64);
        if (lane >= off) incl += t;
    }
    if (wid == 0 && lane == 63) w0sum = incl;
    __syncthreads();
    int excl = incl - v + (wid ? w0sum : 0);
    if (tid < nb) blk_off[tid] = excl;
    if (tid == nb - 1) *row_ptr_n = excl + v;
}

// Pass 3: add block offsets.
__global__ __launch_bounds__(1024) void scan3_kernel(
    int* __restrict__ row_ptr, const int* __restrict__ blk_off, int n) {
    int i = blockIdx.x * 1024 + threadIdx.x;
    if (i < n) row_ptr[i] += blk_off[blockIdx.x];
}

__global__ void fill_kernel(const int* __restrict__ ei, int E, int n,
                            const int* __restrict__ mode,
                            const int* __restrict__ row_ptr,
                            int* __restrict__ cursor,
                            int* __restrict__ csr_src) {
    int e = blockIdx.x * blockDim.x + threadIdx.x;
    if (e >= E) return;
    int m = *mode;
    int s = m ? ei[2 * e] : ei[e];
    int d = m ? ei[2 * (E + e)] : ei[E + e];
    if ((unsigned)d >= (unsigned)n || (unsigned)s >= (unsigned)n) return;
    int pos = atomicAdd(&cursor[d], 1);
    csr_src[row_ptr[d] + pos] = s;
}

// fp32 -> fp16 conversion, 8 elements/thread.
__global__ void f2h_kernel(const float* __restrict__ in,
                           __half* __restrict__ out, int count8) {
    int i = blockIdx.x * blockDim.x + threadIdx.x;
    if (i >= count8) return;
    float4 a = ((const float4*)in)[2 * i];
    float4 b = ((const float4*)in)[2 * i + 1];
    __half2 h[4];
    h[0] = __floats2half2_rn(a.x, a.y);
    h[1] = __floats2half2_rn(a.z, a.w);
    h[2] = __floats2half2_rn(b.x, b.y);
    h[3] = __floats2half2_rn(b.z, b.w);
    ((float4*)out)[i] = *(float4*)h;
}

// One wave per node; lane holds a half2 (128 cols). 8-wide edge unroll.
// Src index scalarized via readfirstlane: SGPR base + lane offset loads,
// dinv[s] via scalar load. out(fp16) = di * (di*x[i] + sum_e dinv[s]*x[s])
__global__ __launch_bounds__(256) void agg_kernel(
    const __half* __restrict__ xh, const float* __restrict__ dinv,
    const int* __restrict__ row_ptr, const int* __restrict__ csr_src,
    __half* __restrict__ outh, int n) {
    int wave = (int)((blockIdx.x * blockDim.x + threadIdx.x) >> 6);
    int lane = threadIdx.x & 63;
    if (wave >= n) return;
    const __half2* x2 = (const __half2*)xh;
    float di = dinv[wave];
    float2 xf = __half22float2(x2[((size_t)wave << 6) + lane]);
    float accx = 0.f, accy = 0.f;
    int e = row_ptr[wave], end = row_ptr[wave + 1];
    for (; e + 8 <= end; e += 8) {
        int s[8];
        float w[8];
        float2 u[8];
#pragma unroll
        for (int k = 0; k < 8; ++k)
            s[k] = __builtin_amdgcn_readfirstlane(csr_src[e + k]);
#pragma unroll
        for (int k = 0; k < 8; ++k) w[k] = dinv[s[k]];
#pragma unroll
        for (int k = 0; k < 8; ++k)
            u[k] = __half22float2(x2[((size_t)s[k] << 6) + lane]);
#pragma unroll
        for (int k = 0; k < 8; ++k) {
            accx += w[k] * u[k].x;
            accy += w[k] * u[k].y;
        }
    }
    for (; e < end; ++e) {
        int s = __builtin_amdgcn_readfirstlane(csr_src[e]);
        float w = dinv[s];
        float2 u = __half22float2(x2[((size_t)s << 6) + lane]);
        accx += w * u.x;
        accy += w * u.y;
    }
    __half2 o = __floats2half2_rn(di * (di * xf.x + accx),
                                  di * (di * xf.y + accy));
    ((__half2*)outh)[((size_t)wave << 6) + lane] = o;
}

// ---------------------------------------------------------------------------
// Pack f32 weights into fp16 MFMA B-fragment order.
// b_frag for (nt,kt) at lane l must hold B[k][c] for
//   k = kt*32 + (l>>4)*8 + e  (e=0..7),  c = nt*16 + (l&15).
// dst[((nt*4+kt)*64 + lane)*8 + e]. One thread per (nt,kt,lane) = 2048.
// Wb == nullptr: single 128-col matrix Wa (ld 128).
// Wb != nullptr: cols 0..63 from Wa, 64..127 from Wb (each ld 64).
// ---------------------------------------------------------------------------
__global__ void packw_kernel(const float* __restrict__ Wa,
                             const float* __restrict__ Wb,
                             __half* __restrict__ dst) {
    int t = blockIdx.x * 256 + threadIdx.x;   // 0..2047
    int lane = t & 63;
    int fk = t >> 6;          // nt*4 + kt
    int kt = fk & 3, nt = fk >> 2;
    int k0 = kt * 32 + ((lane >> 4) << 3);
    int c = nt * 16 + (lane & 15);
    const float* W;
    int ldw, cc;
    if (Wb) {
        W = (c < 64) ? Wa : Wb;
        cc = c & 63;
        ldw = 64;
    } else {
        W = Wa;
        cc = c;
        ldw = 128;
    }
    __half tmp[8];
#pragma unroll
    for (int e = 0; e < 8; ++e)
        tmp[e] = __float2half(W[(size_t)(k0 + e) * ldw + cc]);
    *(float4*)(dst + (size_t)t * 8) = *(float4*)tmp;
}

__global__ void packb_kernel(const float* __restrict__ bmu,
                             const float* __restrict__ blv,
                             float* __restrict__ bcomb) {
    int i = threadIdx.x;  // 128
    bcomb[i] = (i < 64) ? bmu[i] : blv[i - 64];
}

// ---------------------------------------------------------------------------
// MFMA GEMM: A [n x 128] fp16 row-major  @  Wp (packed fp16 frags, 128x128).
// 4 waves/block; each wave computes a 16-row x 128-col strip.
// Fragment layouts (guide §3, m89-verified C/D):
//   A: lane holds row (lane&15), k = kt*32 + (lane>>4)*8 + e
//   C: col = lane&15, row = (lane>>4)*4 + reg
// EPI 0: fp16 output [n x 128], + bias, relu.
// EPI 1: f32 split output: cols 0..63 -> outa [n x 64], 64..127 -> outb.
// ---------------------------------------------------------------------------
template <int EPI>
__global__ __launch_bounds__(256) void gemm_mfma_kernel(
    const __half* __restrict__ A, const __half* __restrict__ Wp,
    const float* __restrict__ bias, void* __restrict__ outa,
    void* __restrict__ outb, int n) {
    int lane = threadIdx.x & 63;
    int wv = threadIdx.x >> 6;
    int m0 = (blockIdx.x * 4 + wv) * 16;
    if (m0 >= n) return;
    int row_a = m0 + (lane & 15);
    if (row_a >= n) row_a = n - 1;              // clamp; stores guarded
    const half8* Arow = (const half8*)(A + (size_t)row_a * 128);
    half8 afr[4];
#pragma unroll
    for (int kt = 0; kt < 4; ++kt) afr[kt] = Arow[kt * 4 + (lane >> 4)];

    const half8* Wf = (const half8*)Wp;
    int colw = lane & 15;
    int rbase = m0 + ((lane >> 4) << 2);

#pragma unroll
    for (int nt = 0; nt < 8; ++nt) {
        f32x4 acc = {0.f, 0.f, 0.f, 0.f};
#pragma unroll
        for (int kt = 0; kt < 4; ++kt)
            acc = __builtin_amdgcn_mfma_f32_16x16x32_f16(
                afr[kt], Wf[(nt * 4 + kt) * 64 + lane], acc, 0, 0, 0);
        int c = nt * 16 + colw;
        float bv = bias[c];
        if (EPI == 0) {
            __half* o = (__half*)outa;
#pragma unroll
            for (int e = 0; e < 4; ++e) {
                int r = rbase + e;
                if (r < n) {
                    float v = fmaxf(acc[e] + bv, 0.f);
                    o[(size_t)r * 128 + c] = __float2half(v);
                }
            }
        } else {
            float* o = (c < 64) ? (float*)outa : (float*)outb;
            int cc = c & 63;
#pragma unroll
            for (int e = 0; e < 4; ++e) {
                int r = rbase + e;
                if (r < n) o[(size_t)r * 64 + cc] = acc[e] + bv;
            }
        }
    }
}

extern "C" void kernel_launch(void* const* d_in, const int* in_sizes, int n_in,
                              void* d_out, int out_size, void* d_ws, size_t ws_size,
                              hipStream_t stream) {
    const float* x   = (const float*)d_in[0];
    const int*   ei  = (const int*)d_in[1];
    const float* W1  = (const float*)d_in[2];
    const float* b1  = (const float*)d_in[3];
    const float* Wmu = (const float*)d_in[4];
    const float* bmu = (const float*)d_in[5];
    const float* Wlv = (const float*)d_in[6];
    const float* blv = (const float*)d_in[7];
    float* out = (float*)d_out;

    const int n = in_sizes[0] / 128;   // 100000
    const int E = in_sizes[1] / 2;     // 1600000
    const int nb = (n + 1023) / 1024;  // scan blocks (98)

    char* ws = (char*)d_ws;
    size_t off = 0;
    auto alloc = [&](size_t bytes) -> void* {
        void* p = ws + off;
        off += (bytes + 255) & ~(size_t)255;
        return p;
    };
    int*   mode    = (int*)alloc(256);
    int*   counts  = (int*)alloc((size_t)n * 4);
    int*   cursor  = (int*)alloc((size_t)n * 4);
    int*   row_ptr = (int*)alloc((size_t)(n + 1) * 4);
    int*   blk     = (int*)alloc((size_t)nb * 4);
    int*   blk_off = (int*)alloc((size_t)nb * 4);
    float* dinv    = (float*)alloc((size_t)n * 4);
    int*   csr_src = (int*)alloc((size_t)E * 4);
    __half* xh     = (__half*)alloc((size_t)n * 128 * 2);  // x fp16, then h fp16
    __half* bufAh  = (__half*)alloc((size_t)n * 128 * 2);  // agg outputs (fp16)
    __half* W1p    = (__half*)alloc(128 * 128 * 2);        // packed W1
    __half* W2p    = (__half*)alloc(128 * 128 * 2);        // packed [Wmu|Wlv]
    float* bcomb   = (float*)alloc(128 * 4);               // [bmu|blv]

    hipMemsetAsync(counts, 0, (size_t)n * 4, stream);
    hipMemsetAsync(cursor, 0, (size_t)n * 4, stream);

    detect_kernel<<<1, 64, 0, stream>>>(ei, mode);

    int eb = (E + 255) / 256;
    count_kernel<<<eb, 256, 0, stream>>>(ei, E, n, mode, counts);
    scan1_kernel<<<nb, 1024, 0, stream>>>(counts, row_ptr, blk, dinv, n);
    scan2_kernel<<<1, 128, 0, stream>>>(blk, blk_off, row_ptr + n, nb);
    scan3_kernel<<<nb, 1024, 0, stream>>>(row_ptr, blk_off, n);
    fill_kernel<<<eb, 256, 0, stream>>>(ei, E, n, mode, row_ptr, cursor, csr_src);

    // Weight packing (tiny, independent of graph work)
    packw_kernel<<<8, 256, 0, stream>>>(W1, nullptr, W1p);
    packw_kernel<<<8, 256, 0, stream>>>(Wmu, Wlv, W2p);
    packb_kernel<<<1, 128, 0, stream>>>(bmu, blv, bcomb);

    int count8 = n * 16;  // n*128/8
    f2h_kernel<<<(count8 + 255) / 256, 256, 0, stream>>>(x, xh, count8);

    int aggBlocks = (n + 3) / 4;  // 4 waves/block, 1 wave/node
    int gb = (n + 63) / 64;       // MFMA gemm blocks: 64 rows/block

    // bufAh = agg(x)  (fp16)
    agg_kernel<<<aggBlocks, 256, 0, stream>>>(xh, dinv, row_ptr, csr_src,
                                              bufAh, n);
    // h(fp16, into xh) = relu(bufAh @ W1 + b1)
    gemm_mfma_kernel<0><<<gb, 256, 0, stream>>>(bufAh, W1p, b1, xh, nullptr, n);
    // bufAh = agg(h)
    agg_kernel<<<aggBlocks, 256, 0, stream>>>(xh, dinv, row_ptr, csr_src,
                                              bufAh, n);
    // mu / logvar fused: read ha once, write both output slabs (f32)
    gemm_mfma_kernel<1><<<gb, 256, 0, stream>>>(bufAh, W2p, bcomb,
                                                out, out + (size_t)n * 64, n);
}

// Round 6
// 342.798 us; speedup vs baseline: 3.3464x; 1.0857x over previous
//
#include <hip/hip_runtime.h>
#include <hip/hip_fp16.h>

// ---------------------------------------------------------------------------
// VGAE encoder: two GCN propagations + dense transforms.
// agg commutes with the right-multiply, so aggregate once per layer and do
// the GEMMs afterwards. Gathers and intermediate features are fp16 (halves
// random-gather bytes); GEMMs run on MFMA f16 with fp32 accumulation.
// CSR build uses a two-level counting sort so every scatter window is
// L2-resident (direct random scatter into 6.4 MB showed 17x write-amp).
// ---------------------------------------------------------------------------

using half8 = __attribute__((ext_vector_type(8))) _Float16;
using f32x4 = __attribute__((ext_vector_type(4))) float;

// Detect whether edge_index arrived as int64 (odd int32 words all zero) or
// int32. Wave-parallel. Writes mode=1 for int64, 0 for int32.
__global__ void detect_kernel(const int* __restrict__ ei, int* __restrict__ mode) {
    int lane = threadIdx.x & 63;
    int any = 0;
    for (int k = lane; k < 1024; k += 64) any |= ei[2 * k + 1];
    unsigned long long b = __ballot(any != 0);
    if (threadIdx.x == 0) *mode = (b == 0ull) ? 1 : 0;
}

__global__ void count_kernel(const int* __restrict__ ei, int E, int n,
                             const int* __restrict__ mode,
                             int* __restrict__ counts) {
    int e = blockIdx.x * blockDim.x + threadIdx.x;
    if (e >= E) return;
    int m = *mode;
    int d = m ? ei[2 * (E + e)] : ei[E + e];
    if ((unsigned)d >= (unsigned)n) return;  // safety
    atomicAdd(&counts[d], 1);
}

// Pass 1: per-block (1024-wide) exclusive scan of counts into row_ptr
// (block-local base), block totals into blk. Also computes dinv.
__global__ __launch_bounds__(1024) void scan1_kernel(
    const int* __restrict__ counts, int* __restrict__ row_ptr,
    int* __restrict__ blk, float* __restrict__ dinv, int n) {
    __shared__ int woff[17];
    int tid = threadIdx.x, lane = tid & 63, wid = tid >> 6;
    int i = blockIdx.x * 1024 + tid;
    int v = (i < n) ? counts[i] : 0;
    if (i < n) dinv[i] = rsqrtf((float)(v + 1));  // +1 self-loop
    int incl = v;
#pragma unroll
    for (int off = 1; off < 64; off <<= 1) {
        int t = __shfl_up(incl, off, 64);
        if (lane >= off) incl += t;
    }
    if (lane == 63) woff[wid + 1] = incl;
    __syncthreads();
    if (tid == 0) {
        int acc = 0;
        woff[0] = 0;
#pragma unroll
        for (int w = 1; w <= 16; ++w) { acc += woff[w]; woff[w] = acc; }
        blk[blockIdx.x] = acc;
    }
    __syncthreads();
    if (i < n) row_ptr[i] = woff[wid] + incl - v;  // block-local exclusive
}

// Pass 2: exclusive scan of nb (<=128) block totals; writes grand total to
// row_ptr_n (= row_ptr + n).
__global__ void scan2_kernel(const int* __restrict__ blk,
                             int* __restrict__ blk_off,
                             int* __restrict__ row_ptr_n, int nb) {
    __shared__ int w0sum;
    int tid = threadIdx.x, lane = tid & 63, wid = tid >> 6;
    int v = (tid < nb) ? blk[tid] : 0;
    int incl = v;
#pragma unroll
    for (int off = 1; off < 64; off <<= 1) {
        int t = __shfl_up(incl, off, 64);
        if (lane >= off) incl += t;
    }
    if (wid == 0 && lane == 63) w0sum = incl;
    __syncthreads();
    int excl = incl - v + (wid ? w0sum : 0);
    if (tid < nb) blk_off[tid] = excl;
    if (tid == nb - 1) *row_ptr_n = excl + v;
}

// Pass 3: add block offsets.
__global__ __launch_bounds__(1024) void scan3_kernel(
    int* __restrict__ row_ptr, const int* __restrict__ blk_off, int n) {
    int i = blockIdx.x * 1024 + threadIdx.x;
    if (i < n) row_ptr[i] += blk_off[blockIdx.x];
}

// Bucket cursors start at each bucket's CSR base (buckets = 256 dst nodes).
__global__ void bucket_base_kernel(const int* __restrict__ row_ptr,
                                   int* __restrict__ cur, int n, int K) {
    int b = blockIdx.x * blockDim.x + threadIdx.x;
    if (b < K) {
        int node = b << 8;
        if (node > n) node = n;
        cur[b] = row_ptr[node];
    }
}

// Partition: LDS-histogram 4096 edges into K buckets, reserve contiguous
// ranges with one global atomic per (block,bucket), write (s,d) pairs
// line-dense into the bucket's region of pair_buf (laid out like the CSR).
__global__ __launch_bounds__(256) void partition_kernel(
    const int* __restrict__ ei, int E, int n, const int* __restrict__ mode,
    int* __restrict__ cur, int2* __restrict__ pairs) {
    __shared__ int hist[512];
    __shared__ int base[512];
    int t = threadIdx.x;
    for (int i = t; i < 512; i += 256) hist[i] = 0;
    __syncthreads();
    int m = *mode;
    int e0 = blockIdx.x * 4096;
    int s_[16], d_[16], o_[16];
#pragma unroll
    for (int k = 0; k < 16; ++k) {
        int e = e0 + k * 256 + t;
        d_[k] = -1;
        if (e < E) {
            int s = m ? ei[2 * e] : ei[e];
            int d = m ? ei[2 * (E + e)] : ei[E + e];
            if ((unsigned)d < (unsigned)n && (unsigned)s < (unsigned)n) {
                s_[k] = s;
                d_[k] = d;
                o_[k] = atomicAdd(&hist[d >> 8], 1);
            }
        }
    }
    __syncthreads();
    int K = (n + 255) >> 8;
    for (int b = t; b < K; b += 256) {
        int h = hist[b];
        base[b] = h ? atomicAdd(&cur[b], h) : 0;
    }
    __syncthreads();
#pragma unroll
    for (int k = 0; k < 16; ++k) {
        if (d_[k] >= 0) {
            int b = d_[k] >> 8;
            pairs[(size_t)(base[b] + o_[k])] = make_int2(s_[k], d_[k]);
        }
    }
}

// Place: one block per bucket; sequential pair read, scatter into the
// bucket's 16KB csr window (+1KB cursor window) -- all L2-resident.
__global__ __launch_bounds__(512) void place_kernel(
    const int2* __restrict__ pairs, const int* __restrict__ row_ptr,
    int* __restrict__ cursor, int* __restrict__ csr_src, int n) {
    int b = blockIdx.x;
    int lo = b << 8, hi = lo + 256;
    if (lo > n) lo = n;
    if (hi > n) hi = n;
    int beg = row_ptr[lo], end = row_ptr[hi];
    for (int i = beg + threadIdx.x; i < end; i += 512) {
        int2 p = pairs[i];
        int pos = atomicAdd(&cursor[p.y], 1);
        csr_src[row_ptr[p.y] + pos] = p.x;
    }
}

// fp32 -> fp16 conversion, 8 elements/thread.
__global__ void f2h_kernel(const float* __restrict__ in,
                           __half* __restrict__ out, int count8) {
    int i = blockIdx.x * blockDim.x + threadIdx.x;
    if (i >= count8) return;
    float4 a = ((const float4*)in)[2 * i];
    float4 b = ((const float4*)in)[2 * i + 1];
    __half2 h[4];
    h[0] = __floats2half2_rn(a.x, a.y);
    h[1] = __floats2half2_rn(a.z, a.w);
    h[2] = __floats2half2_rn(b.x, b.y);
    h[3] = __floats2half2_rn(b.z, b.w);
    ((float4*)out)[i] = *(float4*)h;
}

// One wave per node; lane holds a half2 (128 cols). 8-wide edge unroll.
// Src index scalarized via readfirstlane: SGPR base + lane offset loads,
// dinv[s] via scalar load. out(fp16) = di * (di*x[i] + sum_e dinv[s]*x[s])
__global__ __launch_bounds__(256) void agg_kernel(
    const __half* __restrict__ xh, const float* __restrict__ dinv,
    const int* __restrict__ row_ptr, const int* __restrict__ csr_src,
    __half* __restrict__ outh, int n) {
    int wave = (int)((blockIdx.x * blockDim.x + threadIdx.x) >> 6);
    int lane = threadIdx.x & 63;
    if (wave >= n) return;
    const __half2* x2 = (const __half2*)xh;
    float di = dinv[wave];
    float2 xf = __half22float2(x2[((size_t)wave << 6) + lane]);
    float accx = 0.f, accy = 0.f;
    int e = row_ptr[wave], end = row_ptr[wave + 1];
    for (; e + 8 <= end; e += 8) {
        int s[8];
        float w[8];
        float2 u[8];
#pragma unroll
        for (int k = 0; k < 8; ++k)
            s[k] = __builtin_amdgcn_readfirstlane(csr_src[e + k]);
#pragma unroll
        for (int k = 0; k < 8; ++k) w[k] = dinv[s[k]];
#pragma unroll
        for (int k = 0; k < 8; ++k)
            u[k] = __half22float2(x2[((size_t)s[k] << 6) + lane]);
#pragma unroll
        for (int k = 0; k < 8; ++k) {
            accx += w[k] * u[k].x;
            accy += w[k] * u[k].y;
        }
    }
    for (; e < end; ++e) {
        int s = __builtin_amdgcn_readfirstlane(csr_src[e]);
        float w = dinv[s];
        float2 u = __half22float2(x2[((size_t)s << 6) + lane]);
        accx += w * u.x;
        accy += w * u.y;
    }
    __half2 o = __floats2half2_rn(di * (di * xf.x + accx),
                                  di * (di * xf.y + accy));
    ((__half2*)outh)[((size_t)wave << 6) + lane] = o;
}

// ---------------------------------------------------------------------------
// Pack f32 weights into fp16 MFMA B-fragment order.
// b_frag for (nt,kt) at lane l must hold B[k][c] for
//   k = kt*32 + (l>>4)*8 + e  (e=0..7),  c = nt*16 + (l&15).
// dst[((nt*4+kt)*64 + lane)*8 + e]. One thread per (nt,kt,lane) = 2048.
// Wb == nullptr: single 128-col matrix Wa (ld 128).
// Wb != nullptr: cols 0..63 from Wa, 64..127 from Wb (each ld 64).
// ---------------------------------------------------------------------------
__global__ void packw_kernel(const float* __restrict__ Wa,
                             const float* __restrict__ Wb,
                             __half* __restrict__ dst) {
    int t = blockIdx.x * 256 + threadIdx.x;   // 0..2047
    int lane = t & 63;
    int fk = t >> 6;          // nt*4 + kt
    int kt = fk & 3, nt = fk >> 2;
    int k0 = kt * 32 + ((lane >> 4) << 3);
    int c = nt * 16 + (lane & 15);
    const float* W;
    int ldw, cc;
    if (Wb) {
        W = (c < 64) ? Wa : Wb;
        cc = c & 63;
        ldw = 64;
    } else {
        W = Wa;
        cc = c;
        ldw = 128;
    }
    __half tmp[8];
#pragma unroll
    for (int e = 0; e < 8; ++e)
        tmp[e] = __float2half(W[(size_t)(k0 + e) * ldw + cc]);
    *(float4*)(dst + (size_t)t * 8) = *(float4*)tmp;
}

__global__ void packb_kernel(const float* __restrict__ bmu,
                             const float* __restrict__ blv,
                             float* __restrict__ bcomb) {
    int i = threadIdx.x;  // 128
    bcomb[i] = (i < 64) ? bmu[i] : blv[i - 64];
}

// ---------------------------------------------------------------------------
// MFMA GEMM: A [n x 128] fp16 row-major  @  Wp (packed fp16 frags, 128x128).
// 4 waves/block; each wave computes a 16-row x 128-col strip.
// Fragment layouts (guide §3, m89-verified C/D):
//   A: lane holds row (lane&15), k = kt*32 + (lane>>4)*8 + e
//   C: col = lane&15, row = (lane>>4)*4 + reg
// EPI 0: fp16 output [n x 128], + bias, relu.
// EPI 1: f32 split output: cols 0..63 -> outa [n x 64], 64..127 -> outb.
// ---------------------------------------------------------------------------
template <int EPI>
__global__ __launch_bounds__(256) void gemm_mfma_kernel(
    const __half* __restrict__ A, const __half* __restrict__ Wp,
    const float* __restrict__ bias, void* __restrict__ outa,
    void* __restrict__ outb, int n) {
    int lane = threadIdx.x & 63;
    int wv = threadIdx.x >> 6;
    int m0 = (blockIdx.x * 4 + wv) * 16;
    if (m0 >= n) return;
    int row_a = m0 + (lane & 15);
    if (row_a >= n) row_a = n - 1;              // clamp; stores guarded
    const half8* Arow = (const half8*)(A + (size_t)row_a * 128);
    half8 afr[4];
#pragma unroll
    for (int kt = 0; kt < 4; ++kt) afr[kt] = Arow[kt * 4 + (lane >> 4)];

    const half8* Wf = (const half8*)Wp;
    int colw = lane & 15;
    int rbase = m0 + ((lane >> 4) << 2);

#pragma unroll
    for (int nt = 0; nt < 8; ++nt) {
        f32x4 acc = {0.f, 0.f, 0.f, 0.f};
#pragma unroll
        for (int kt = 0; kt < 4; ++kt)
            acc = __builtin_amdgcn_mfma_f32_16x16x32_f16(
                afr[kt], Wf[(nt * 4 + kt) * 64 + lane], acc, 0, 0, 0);
        int c = nt * 16 + colw;
        float bv = bias[c];
        if (EPI == 0) {
            __half* o = (__half*)outa;
#pragma unroll
            for (int e = 0; e < 4; ++e) {
                int r = rbase + e;
                if (r < n) {
                    float v = fmaxf(acc[e] + bv, 0.f);
                    o[(size_t)r * 128 + c] = __float2half(v);
                }
            }
        } else {
            float* o = (c < 64) ? (float*)outa : (float*)outb;
            int cc = c & 63;
#pragma unroll
            for (int e = 0; e < 4; ++e) {
                int r = rbase + e;
                if (r < n) o[(size_t)r * 64 + cc] = acc[e] + bv;
            }
        }
    }
}

extern "C" void kernel_launch(void* const* d_in, const int* in_sizes, int n_in,
                              void* d_out, int out_size, void* d_ws, size_t ws_size,
                              hipStream_t stream) {
    const float* x   = (const float*)d_in[0];
    const int*   ei  = (const int*)d_in[1];
    const float* W1  = (const float*)d_in[2];
    const float* b1  = (const float*)d_in[3];
    const float* Wmu = (const float*)d_in[4];
    const float* bmu = (const float*)d_in[5];
    const float* Wlv = (const float*)d_in[6];
    const float* blv = (const float*)d_in[7];
    float* out = (float*)d_out;

    const int n = in_sizes[0] / 128;   // 100000
    const int E = in_sizes[1] / 2;     // 1600000
    const int nb = (n + 1023) / 1024;  // scan blocks (98)
    const int K  = (n + 255) >> 8;     // dst buckets (391)

    char* ws = (char*)d_ws;
    size_t off = 0;
    auto alloc = [&](size_t bytes) -> void* {
        void* p = ws + off;
        off += (bytes + 255) & ~(size_t)255;
        return p;
    };
    int*   mode    = (int*)alloc(256);
    int*   counts  = (int*)alloc((size_t)n * 4);
    int*   cursor  = (int*)alloc((size_t)n * 4);
    int*   row_ptr = (int*)alloc((size_t)(n + 1) * 4);
    int*   blk     = (int*)alloc((size_t)nb * 4);
    int*   blk_off = (int*)alloc((size_t)nb * 4);
    int*   bcur    = (int*)alloc((size_t)K * 4);
    float* dinv    = (float*)alloc((size_t)n * 4);
    int*   csr_src = (int*)alloc((size_t)E * 4);
    int2*  pairs   = (int2*)alloc((size_t)E * 8);
    __half* xh     = (__half*)alloc((size_t)n * 128 * 2);  // x fp16, then h fp16
    __half* bufAh  = (__half*)alloc((size_t)n * 128 * 2);  // agg outputs (fp16)
    __half* W1p    = (__half*)alloc(128 * 128 * 2);        // packed W1
    __half* W2p    = (__half*)alloc(128 * 128 * 2);        // packed [Wmu|Wlv]
    float* bcomb   = (float*)alloc(128 * 4);               // [bmu|blv]

    hipMemsetAsync(counts, 0, (size_t)n * 4, stream);
    hipMemsetAsync(cursor, 0, (size_t)n * 4, stream);

    detect_kernel<<<1, 64, 0, stream>>>(ei, mode);

    int eb = (E + 255) / 256;
    count_kernel<<<eb, 256, 0, stream>>>(ei, E, n, mode, counts);
    scan1_kernel<<<nb, 1024, 0, stream>>>(counts, row_ptr, blk, dinv, n);
    scan2_kernel<<<1, 128, 0, stream>>>(blk, blk_off, row_ptr + n, nb);
    scan3_kernel<<<nb, 1024, 0, stream>>>(row_ptr, blk_off, n);

    // CSR build: bucket partition (line-dense writes) + L2-local place.
    bucket_base_kernel<<<(K + 255) / 256, 256, 0, stream>>>(row_ptr, bcur, n, K);
    partition_kernel<<<(E + 4095) / 4096, 256, 0, stream>>>(ei, E, n, mode,
                                                            bcur, pairs);
    place_kernel<<<K, 512, 0, stream>>>(pairs, row_ptr, cursor, csr_src, n);

    // Weight packing (tiny, independent of graph work)
    packw_kernel<<<8, 256, 0, stream>>>(W1, nullptr, W1p);
    packw_kernel<<<8, 256, 0, stream>>>(Wmu, Wlv, W2p);
    packb_kernel<<<1, 128, 0, stream>>>(bmu, blv, bcomb);

    int count8 = n * 16;  // n*128/8
    f2h_kernel<<<(count8 + 255) / 256, 256, 0, stream>>>(x, xh, count8);

    int aggBlocks = (n + 3) / 4;  // 4 waves/block, 1 wave/node
    int gb = (n + 63) / 64;       // MFMA gemm blocks: 64 rows/block

    // bufAh = agg(x)  (fp16)
    agg_kernel<<<aggBlocks, 256, 0, stream>>>(xh, dinv, row_ptr, csr_src,
                                              bufAh, n);
    // h(fp16, into xh) = relu(bufAh @ W1 + b1)
    gemm_mfma_kernel<0><<<gb, 256, 0, stream>>>(bufAh, W1p, b1, xh, nullptr, n);
    // bufAh = agg(h)
    agg_kernel<<<aggBlocks, 256, 0, stream>>>(xh, dinv, row_ptr, csr_src,
                                              bufAh, n);
    // mu / logvar fused: read ha once, write both output slabs (f32)
    gemm_mfma_kernel<1><<<gb, 256, 0, stream>>>(bufAh, W2p, bcomb,
                                                out, out + (size_t)n * 64, n);
}